// Round 1
// 233.277 us; speedup vs baseline: 1.0185x; 1.0185x over previous
//
#include <hip/hip_runtime.h>

// Problem constants (fixed by setup_inputs: B=4, S=2048, DIN=DOUT=4096)
constexpr int K0   = 16;
constexpr int DIN  = 4096;
constexpr int DOUT = 4096;

constexpr int BLOCK          = 256;
constexpr int CPT            = 4;              // cols per thread (float4 store)
constexpr int COLS_PER_BLOCK = BLOCK * CPT;    // 1024
constexpr int ROWS           = 16;             // rows per block -> grid.y = 512

typedef float vfloat4 __attribute__((ext_vector_type(4)));

// Math note: tstat = |y1|/sqrt(s2/16) >= 0 (NaN compares False too), TAU < 0,
// so `passed` is identically False and the reference collapses EXACTLY to
//   out[i,j] = dot16(x2[i,0:16], W[j,0:16]) + c,
//   c = sum_{t=16}^{4095} W[0,t]*x2[0,t].
//
// V2 structure: two kernels on one stream (graph-safe, no sync APIs).
//  (1) et_c: one block computes c once, writes to d_ws. Removes the redundant
//      per-block c prologue (8 global loads + reduce + 2 barriers) from all
//      2048 store blocks.
//  (2) et_store: pure write-stream kernel. Scalar c load (L2 broadcast),
//      xk staged via LDS (one barrier), nontemporal float4 stores so the
//      134 MB dead-on-write output doesn't churn L2.

__global__ __launch_bounds__(BLOCK) void et_c(const float* __restrict__ x,
                                              const float* __restrict__ W,
                                              float* __restrict__ c_out) {
    __shared__ float red[4];
    const int tid = threadIdx.x;
    // x+16 and W+16 are 64B-aligned; 1020 float4 pairs over 256 threads = 4 iters.
    const float4* xc = (const float4*)(x + K0);
    const float4* wc = (const float4*)(W + K0);
    float acc = 0.0f;
    const int nq = (DIN - K0) / 4;  // 1020
    for (int t = tid; t < nq; t += BLOCK) {
        float4 a = xc[t], b = wc[t];
        acc = fmaf(a.x, b.x, acc);
        acc = fmaf(a.y, b.y, acc);
        acc = fmaf(a.z, b.z, acc);
        acc = fmaf(a.w, b.w, acc);
    }
    #pragma unroll
    for (int off = 32; off > 0; off >>= 1)
        acc += __shfl_down(acc, off, 64);
    if ((tid & 63) == 0) red[tid >> 6] = acc;
    __syncthreads();
    if (tid == 0) c_out[0] = red[0] + red[1] + red[2] + red[3];
}

__global__ __launch_bounds__(BLOCK) void et_store(const float* __restrict__ x,
                                                  const float* __restrict__ W,
                                                  const float* __restrict__ c_ptr,
                                                  float* __restrict__ out) {
    __shared__ float xk_sh[ROWS][K0];   // 1 KB

    const int tid  = threadIdx.x;
    const int j0   = blockIdx.x * COLS_PER_BLOCK + tid * CPT;
    const int row0 = blockIdx.y * ROWS;

    // Issue the c load early; it's only consumed in the store loop, so the
    // ~L2-hit latency hides under the wk/xk staging below.
    const float c = c_ptr[0];

    // Stage 16 rows of xk (1 KB): lanes 0..63, one float4 each.
    float4 xs;
    if (tid < ROWS * 4) {
        const int r = tid >> 2, q = tid & 3;
        xs = ((const float4*)(x + (size_t)(row0 + r) * DIN))[q];
    }

    // wk for this thread's 4 columns: W[j][0:16], 64B per column (L2-resident
    // after the first y-tile touches it).
    float wk[CPT][K0];
    #pragma unroll
    for (int cc = 0; cc < CPT; ++cc) {
        const float4* wp = (const float4*)(W + (size_t)(j0 + cc) * DIN);
        #pragma unroll
        for (int q = 0; q < K0 / 4; ++q) {
            float4 v = wp[q];
            wk[cc][4 * q + 0] = v.x;
            wk[cc][4 * q + 1] = v.y;
            wk[cc][4 * q + 2] = v.z;
            wk[cc][4 * q + 3] = v.w;
        }
    }

    if (tid < ROWS * 4) {
        const int r = tid >> 2, q = tid & 3;
        float* p = &xk_sh[r][4 * q];
        p[0] = xs.x; p[1] = xs.y; p[2] = xs.z; p[3] = xs.w;
    }
    __syncthreads();   // single barrier in this kernel

    // Store loop: LDS broadcast reads + 64 FMAs + one nontemporal float4
    // store per row. 1 KB/wave/row, fully coalesced.
    #pragma unroll 4
    for (int r = 0; r < ROWS; ++r) {
        float xk[K0];
        #pragma unroll
        for (int q = 0; q < K0 / 4; ++q) {
            vfloat4 v = *((const vfloat4*)&xk_sh[r][4 * q]);  // all lanes same addr
            xk[4 * q + 0] = v[0];
            xk[4 * q + 1] = v[1];
            xk[4 * q + 2] = v[2];
            xk[4 * q + 3] = v[3];
        }

        vfloat4 o;
        #pragma unroll
        for (int cc = 0; cc < CPT; ++cc) {
            float s = c;
            #pragma unroll
            for (int k = 0; k < K0; ++k)
                s = fmaf(xk[k], wk[cc][k], s);
            o[cc] = s;
        }
        __builtin_nontemporal_store(
            o, (vfloat4*)(out + (size_t)(row0 + r) * DOUT + j0));
    }
}

extern "C" void kernel_launch(void* const* d_in, const int* in_sizes, int n_in,
                              void* d_out, int out_size, void* d_ws, size_t ws_size,
                              hipStream_t stream) {
    const float* x = (const float*)d_in[0];   // (8192, 4096) flattened
    const float* W = (const float*)d_in[1];   // (4096, 4096)
    float* out     = (float*)d_out;           // (8192, 4096)
    float* c_buf   = (float*)d_ws;            // 4 bytes of workspace

    const int nrows = in_sizes[0] / DIN;      // 8192

    et_c<<<dim3(1), BLOCK, 0, stream>>>(x, W, c_buf);

    dim3 grid(DOUT / COLS_PER_BLOCK, nrows / ROWS);  // (4, 512)
    et_store<<<grid, BLOCK, 0, stream>>>(x, W, c_buf, out);
}